// Round 11
// baseline (373.003 us; speedup 1.0000x reference)
//
#include <hip/hip_runtime.h>
#include <hip/hip_bf16.h>

// ============================================================================
// B=512, M=40, D=64. Three bilinear layers (200 outputs each):
//   out[o,d] = relu(bias[o] + sum_c W[o,c]*U[c,d]), U[(m,n),d] = x[m,d]*h[n,d]
// R11: 32x32x16 MFMA (operand layout verified in R10) + SHARED LDS U-build
// (structure verified in R5). Per b: C[224,64] = W'[224,K'] x U[K',64],
// K' = 40*NPAD (NPAD = 40 / 104, zero-padded cols).
//   U slab per K=32 kstep: [bb][d][32 bf16 k-slots], rows padded to 18 dwords
//   (72B): plain k-contiguous, no XOR perm. Build (R5 semantics): wave wv
//   writes k-slots 4wv..4wv+3 = one b64 at dword 2wv, both batches.
//   Consume: B-frag = one b128 per (j,h): lane l reads row d = 32h + (l&31),
//   dwords 8j + 4*(l>>5) -> 8 k-consecutive bf16. A-frags from global
//   (frag-contiguous prepass, R10-verified incl. compact mt6 pack).
// Block = 2 batches, 512 thr = 8 waves: wn = wv&1 (batch), gm = wv>>1 owns
//   m-tiles {0,1}/{2,3}/{4,5}/{6}; each wave covers BOTH d-halves -> rowsum
//   completes in-wave. 4-kstep static phases, 4 slabs, raw barrier+lgkmcnt.
// ============================================================================

typedef float f32x16 __attribute__((ext_vector_type(16)));
typedef short bf16x8 __attribute__((ext_vector_type(8)));
typedef unsigned int uint;

struct LDSR11 {
    __hip_bfloat16 xs[2][64][44];       // [bb][d][m]            11264 B
    __hip_bfloat16 hs[2][2][64][108];   // [pp][bb][d][n]        55296 B
    uint U[4][2][64][18];               // [slab][bb][d][18dw]   36864 B
};                                      // total 103424 B -> 1 block/CU

static __device__ __forceinline__ float bflo(uint u) {
    uint v = u << 16; return __builtin_bit_cast(float, v);
}
static __device__ __forceinline__ float bfhi(uint u) {
    uint v = u & 0xffff0000u; return __builtin_bit_cast(float, v);
}
static __device__ __forceinline__ uint pk_bf16(float a, float b) {
    uint r; asm("v_cvt_pk_bf16_f32 %0, %1, %2" : "=v"(r) : "v"(a), "v"(b));
    return r;
}

#define PHASE_BAR() do {                                   \
    asm volatile("s_waitcnt lgkmcnt(0)" ::: "memory");     \
    __builtin_amdgcn_sched_barrier(0);                     \
    __builtin_amdgcn_s_barrier();                          \
    __builtin_amdgcn_sched_barrier(0);                     \
} while (0)

// slab dword strides: slab=2304, bb=1152, d=18
template<int NPAD, int NK, int HASH, int ROWLO, int ROWOFF, int HSTR, int HBBS,
         int T, int CP>
__device__ __forceinline__ void layer32(
    LDSR11* L, const bf16x8* __restrict__ pwf, const bf16x8* __restrict__ pwc,
    const float* __restrict__ bias,
    const __hip_bfloat16* __restrict__ hsrc,   // + bb*HBBS + d*HSTR + n
    __hip_bfloat16* __restrict__ hdst,         // hs[dstpp] base (+wn*6912)
    float* __restrict__ outb, int tid, int mt0)
{
    const int lane = tid & 63;
    const int wv = tid >> 6, wn = wv & 1;
    const int l31 = lane & 31, h5 = lane >> 5;

    // consume base: + sl_dw + h*576 + 8*j
    const uint* Ub = &L->U[0][0][0][0];
    const int roff = wn * 1152 + 18 * l31 + 4 * h5;

    // build base (both bb): + sl_dw (+1152 for bb=1)
    uint* wb0 = &L->U[0][0][0][0] + 18 * lane + 2 * wv;

    const __hip_bfloat16* hb0 = hsrc + lane * HSTR;
    const __hip_bfloat16* hb1 = hsrc + HBBS + lane * HSTR;
    const __hip_bfloat16* xb0 = &L->xs[0][lane][0];
    const __hip_bfloat16* xb1 = &L->xs[1][lane][0];

    const f32x16 zz = {0,0,0,0,0,0,0,0,0,0,0,0,0,0,0,0};
    f32x16 acc[T][2];
    #pragma unroll
    for (int t = 0; t < T; ++t) { acc[t][0] = zz; acc[t][1] = zz; }

    // build state: kstep bk covers k-slots c0 = 32*bk + 4*wv .. +3
    int bm = 0, bn = 4 * wv, bk = 0;
    auto build = [&]() {
        if (bk < NK) {
            const int sl_dw = (bk & 3) * 2304;
            float xf0 = __bfloat162float(xb0[bm]);
            float xf1 = __bfloat162float(xb1[bm]);
            uint2 ha = *(const uint2*)(hb0 + bn);
            uint2 hc = *(const uint2*)(hb1 + bn);
            uint2 w0, w1;
            w0.x = pk_bf16(xf0 * bflo(ha.x), xf0 * bfhi(ha.x));
            w0.y = pk_bf16(xf0 * bflo(ha.y), xf0 * bfhi(ha.y));
            w1.x = pk_bf16(xf1 * bflo(hc.x), xf1 * bfhi(hc.x));
            w1.y = pk_bf16(xf1 * bflo(hc.y), xf1 * bfhi(hc.y));
            *(uint2*)(wb0 + sl_dw)        = w0;
            *(uint2*)(wb0 + sl_dw + 1152) = w1;
            bn += 32;
            if (bn >= NPAD) { bn -= NPAD; ++bm; }
            ++bk;
        }
    };

    auto consume = [&](int sl_dw, bf16x8 (*f)[2]) {
        #pragma unroll
        for (int j = 0; j < 2; ++j) {
            bf16x8 bh[2];
            #pragma unroll
            for (int h = 0; h < 2; ++h) {
                union { uint4 u; bf16x8 v; } t4;
                t4.u = *(const uint4*)(Ub + roff + sl_dw + h * 576 + 8 * j);
                bh[h] = t4.v;
            }
            #pragma unroll
            for (int t = 0; t < T; ++t) {
                acc[t][0] = __builtin_amdgcn_mfma_f32_32x32x16_bf16(
                    f[t][j], bh[0], acc[t][0], 0, 0, 0);
                acc[t][1] = __builtin_amdgcn_mfma_f32_32x32x16_bf16(
                    f[t][j], bh[1], acc[t][1], 0, 0, 0);
            }
        }
    };

    const bf16x8* pA[T];
    #pragma unroll
    for (int t = 0; t < T; ++t)
        pA[t] = pwf + (size_t)(mt0 + t) * NK * 2 * 64 + lane;
    const bool act  = (l31 < 8);
    const int  slot = l31 + 8 * h5;
    const bf16x8* pC = pwc + slot;

    auto loadA = [&](bf16x8 (*f)[2], int s) {
        if (s < NK) {
            if (CP) {
                if (act) {
                    f[0][0] = pC[(2 * s) * 16];
                    f[0][1] = pC[(2 * s + 1) * 16];
                }
            } else {
                #pragma unroll
                for (int t = 0; t < T; ++t) {
                    f[t][0] = pA[t][(size_t)(2 * s) * 64];
                    f[t][1] = pA[t][(size_t)(2 * s + 1) * 64];
                }
            }
        }
    };

    bf16x8 fa[T][2], fb[T][2];
    if (CP) {
        union { uint u[4]; bf16x8 v; } fz; fz.u[0]=fz.u[1]=fz.u[2]=fz.u[3]=0u;
        #pragma unroll
        for (int t = 0; t < T; ++t) {
            fa[t][0]=fz.v; fa[t][1]=fz.v; fb[t][0]=fz.v; fb[t][1]=fz.v;
        }
    }
    loadA(fa, 0); loadA(fb, 1);
    build(); build();                 // ksteps 0,1 -> slabs 0,1
    __syncthreads();

    // main: 4-kstep iterations, static slab offsets. NK%4 == 2 for 50/130.
    #pragma unroll 1
    for (int s = 0; s + 4 <= NK; s += 4) {
        // phase A: ksteps s,s+1 (slabs 0,1); builds s+2,s+3 (slabs 2,3)
        consume(0, fa);
        loadA(fa, s + 2);
        consume(2304, fb);
        loadA(fb, s + 3);
        build(); build();
        PHASE_BAR();
        // phase B: ksteps s+2,s+3 (slabs 2,3); builds s+4,s+5 (slabs 0,1)
        consume(4608, fa);
        loadA(fa, s + 4);
        consume(6912, fb);
        loadA(fb, s + 5);
        build(); build();
        PHASE_BAR();
    }
    // tail: 2 ksteps (NK-2, NK-1) in slabs 0,1
    consume(0, fa);
    consume(2304, fb);

    // ---- epilogue: 32x32 C/D layout (R10-verified):
    //      col = lane&31 (+32h per acc half), row = (reg&3)+8*(reg>>2)+4*h5
    __hip_bfloat16* hd0 = hdst + wn * 6912 + l31 * 108;
    __hip_bfloat16* hd1 = hdst + wn * 6912 + (l31 + 32) * 108;
    #pragma unroll
    for (int t = 0; t < T; ++t) {
        #pragma unroll
        for (int reg = 0; reg < 16; ++reg) {
            const int o = 32 * (mt0 + t) + (reg & 3) + 8 * (reg >> 2) + 4 * h5;
            const float bs = bias[o < 200 ? o : 0];
            float r0 = fmaxf(acc[t][0][reg] + bs, 0.f);   // col d = l31
            float r1 = fmaxf(acc[t][1][reg] + bs, 0.f);   // col d = l31+32
            if (HASH && o < 100) {
                hd0[o] = __float2bfloat16(r0);
                hd1[o] = __float2bfloat16(r1);
            }
            float sv = r0 + r1;
            sv += __shfl_xor(sv, 1, 64);
            sv += __shfl_xor(sv, 2, 64);
            sv += __shfl_xor(sv, 4, 64);
            sv += __shfl_xor(sv, 8, 64);
            sv += __shfl_xor(sv, 16, 64);
            if (l31 == 0 && o >= ROWLO && o < 200)
                outb[ROWOFF + (o - ROWLO)] = sv;
        }
    }
}

template<int T, int CP>
__device__ __forceinline__ void run_layers32(
    LDSR11* L,
    const bf16x8* w1f, const bf16x8* w2f, const bf16x8* w3f,
    const bf16x8* w1c, const bf16x8* w2c, const bf16x8* w3c,
    const float* b1, const float* b2, const float* b3,
    float* outb, int tid, int mt0)
{
    layer32< 40,  50, 1, 100,   0,  44, 2816, T, CP>(L, w1f, w1c, b1,
        &L->xs[0][0][0], &L->hs[0][0][0][0], outb, tid, mt0);
    __syncthreads();
    layer32<104, 130, 1, 100, 100, 108, 6912, T, CP>(L, w2f, w2c, b2,
        &L->hs[0][0][0][0], &L->hs[1][0][0][0], outb, tid, mt0);
    __syncthreads();
    layer32<104, 130, 0,   0, 200, 108, 6912, T, CP>(L, w3f, w3c, b3,
        &L->hs[1][0][0][0], &L->hs[0][0][0][0], outb, tid, mt0);
}

__global__ __launch_bounds__(512, 1)
void fused_mfma32(const float* __restrict__ x, const bf16x8* __restrict__ wp,
                  const float* __restrict__ b1, const float* __restrict__ b2,
                  const float* __restrict__ b3, float* __restrict__ out)
{
    __shared__ LDSR11 L;
    const int tid = threadIdx.x, bi = blockIdx.x;

    // zero hs pad cols 100..107 (build reads up to col 103; W' zero there)
    for (int i = tid; i < 2 * 2 * 64 * 8; i += 512) {
        int c  = i & 7;
        int dd = (i >> 3) & 63;
        int bbp = i >> 9;                     // pp*2 + bb
        L.hs[bbp >> 1][bbp & 1][dd][100 + c] = __float2bfloat16(0.f);
    }
    // stage x (2 batches), fp32 -> bf16, transposed to [d][m]
    const float* xg = x + (size_t)(2 * bi) * 2560;
    for (int i = tid; i < 5120; i += 512) {
        int bb = (i >= 2560) ? 1 : 0;
        int r  = i - bb * 2560;
        L.xs[bb][r & 63][r >> 6] = __float2bfloat16(xg[i]);
    }
    __syncthreads();

    const int wv = tid >> 6, wn = wv & 1, gm = wv >> 1;
    float* outb = out + (size_t)(2 * bi + wn) * 400;

    const bf16x8* w1f = wp;                 // 6*50*2*64   = 38400 frags
    const bf16x8* w2f = wp + 38400;         // 6*130*2*64  = 99840
    const bf16x8* w3f = wp + 138240;        // 99840
    const bf16x8* w1c = wp + 238080;        // 50*2*16     = 1600
    const bf16x8* w2c = wp + 239680;        // 130*2*16    = 4160
    const bf16x8* w3c = wp + 243840;        // 4160 (end 248000)

    if (gm < 3)
        run_layers32<2, 0>(&L, w1f, w2f, w3f, w1c, w2c, w3c,
                           b1, b2, b3, outb, tid, 2 * gm);
    else
        run_layers32<1, 1>(&L, w1f, w2f, w3f, w1c, w2c, w3c,
                           b1, b2, b3, outb, tid, 6);
}

// ---------------------------------------------------------------------------
// Prepass (R10-verified verbatim): W fp32 -> bf16, 32x32-frag-contiguous,
// n padded to NPAD. Full frags (mt 0..5): idx = ((mt*NK+s)*2+j)*64 + lane,
// lane holds W'[32mt+(lane&31)][32s+16j+8*(lane>>5)..+8]. Compact (mt=6,
// rows 192..199): idx = (s*2+j)*16 + slot, row = 192+(slot&7), khalf=slot>>3.
// ---------------------------------------------------------------------------
__global__ void convert_pack32(const float* __restrict__ w1, const float* __restrict__ w2,
                               const float* __restrict__ w3, uint4* __restrict__ outp) {
    int c = blockIdx.x * 256 + threadIdx.x;
    if (c >= 248000) return;
    const float* src; int NK, DIV, NPAD, idx; bool compact;
    if (c < 38400)       { src = w1; NK = 50;  DIV = 40;  NPAD = 40;  idx = c;          compact = false; }
    else if (c < 138240) { src = w2; NK = 130; DIV = 100; NPAD = 104; idx = c - 38400;  compact = false; }
    else if (c < 238080) { src = w3; NK = 130; DIV = 100; NPAD = 104; idx = c - 138240; compact = false; }
    else if (c < 239680) { src = w1; NK = 50;  DIV = 40;  NPAD = 40;  idx = c - 238080; compact = true; }
    else if (c < 243840) { src = w2; NK = 130; DIV = 100; NPAD = 104; idx = c - 239680; compact = true; }
    else                 { src = w3; NK = 130; DIV = 100; NPAD = 104; idx = c - 243840; compact = true; }

    int row, m, n0;
    if (!compact) {
        int lane = idx & 63;
        int fj   = idx >> 6;
        int j    = fj & 1;
        int t2   = fj >> 1;            // mt*NK + s
        int mt   = t2 / NK;
        int s    = t2 - mt * NK;
        row = 32 * mt + (lane & 31);
        int c0 = 32 * s + 16 * j + 8 * (lane >> 5);
        m = c0 / NPAD; n0 = c0 - m * NPAD;
    } else {
        int slot = idx & 15;
        int sj   = idx >> 4;
        int j    = sj & 1;
        int s    = sj >> 1;
        row = 192 + (slot & 7);
        int c0 = 32 * s + 16 * j + 8 * (slot >> 3);
        m = c0 / NPAD; n0 = c0 - m * NPAD;
    }
    uint o[4];
    if (row < 200) {
        const float* p = src + (size_t)row * (40 * DIV) + m * DIV + n0;
        #pragma unroll
        for (int jj = 0; jj < 4; ++jj) {
            float flo = (n0 + 2 * jj     < DIV) ? p[2 * jj]     : 0.f;
            float fhi = (n0 + 2 * jj + 1 < DIV) ? p[2 * jj + 1] : 0.f;
            __hip_bfloat16 lo = __float2bfloat16(flo);
            __hip_bfloat16 hi = __float2bfloat16(fhi);
            o[jj] = (uint)__builtin_bit_cast(unsigned short, lo)
                  | ((uint)__builtin_bit_cast(unsigned short, hi) << 16);
        }
    } else {
        #pragma unroll
        for (int jj = 0; jj < 4; ++jj) o[jj] = 0u;
    }
    uint4 v; v.x = o[0]; v.y = o[1]; v.z = o[2]; v.w = o[3];
    outp[c] = v;
}

// ---------------------------------------------------------------------------
// Fallback (fp32 VALU kernel) if ws too small.
// ---------------------------------------------------------------------------
__global__ __launch_bounds__(512, 1)
void fused_bilinear_kernel(const float* __restrict__ x,
                           const float* __restrict__ w1, const float* __restrict__ b1,
                           const float* __restrict__ w2, const float* __restrict__ b2,
                           const float* __restrict__ w3, const float* __restrict__ b3,
                           float* __restrict__ out) {
    const int b   = blockIdx.x;
    const int tid = threadIdx.x;
    const int d   = tid & 63;
    const int wv  = tid >> 6;

    __shared__ float xs[40][64];
    __shared__ float hs[100][64];

    const float* xb = x + (size_t)b * 40 * 64;
    for (int i = tid; i < 40 * 64; i += 512) ((float*)xs)[i] = xb[i];
    __syncthreads();

    float xr[40];
    #pragma unroll
    for (int m = 0; m < 40; ++m) xr[m] = xs[m][d];
    float hr[100];
    const int o0 = __builtin_amdgcn_readfirstlane(wv * 25);

    for (int oi = 0; oi < 25; ++oi) {
        const int o = o0 + oi;
        const float* __restrict__ wrow = w1 + (size_t)o * 1600;
        float s = b1[o];
        for (int m = 0; m < 40; ++m) {
            const float* __restrict__ wm = wrow + m * 40;
            float a0 = 0.f, a1 = 0.f, a2 = 0.f, a3 = 0.f;
            #pragma unroll
            for (int n = 0; n < 40; n += 4) {
                a0 = fmaf(wm[n + 0], xr[n + 0], a0);
                a1 = fmaf(wm[n + 1], xr[n + 1], a1);
                a2 = fmaf(wm[n + 2], xr[n + 2], a2);
                a3 = fmaf(wm[n + 3], xr[n + 3], a3);
            }
            s = fmaf(xs[m][d], (a0 + a1) + (a2 + a3), s);
        }
        s = fmaxf(s, 0.f);
        if (o < 100) hs[o][d] = s;
        else {
            float r = s;
            #pragma unroll
            for (int off = 32; off > 0; off >>= 1) r += __shfl_xor(r, off, 64);
            if (d == 0) out[(size_t)b * 400 + (o - 100)] = r;
        }
    }
    __syncthreads();
    #pragma unroll
    for (int n = 0; n < 100; ++n) hr[n] = hs[n][d];
    __syncthreads();

    for (int oi = 0; oi < 25; ++oi) {
        const int o = o0 + oi;
        const float* __restrict__ wrow = w2 + (size_t)o * 4000;
        float s = b2[o];
        for (int m = 0; m < 40; ++m) {
            const float* __restrict__ wm = wrow + m * 100;
            float a0 = 0.f, a1 = 0.f, a2 = 0.f, a3 = 0.f;
            #pragma unroll
            for (int n = 0; n < 100; n += 4) {
                a0 = fmaf(wm[n + 0], hr[n + 0], a0);
                a1 = fmaf(wm[n + 1], hr[n + 1], a1);
                a2 = fmaf(wm[n + 2], hr[n + 2], a2);
                a3 = fmaf(wm[n + 3], hr[n + 3], a3);
            }
            s = fmaf(xs[m][d], (a0 + a1) + (a2 + a3), s);
        }
        s = fmaxf(s, 0.f);
        if (o < 100) hs[o][d] = s;
        else {
            float r = s;
            #pragma unroll
            for (int off = 32; off > 0; off >>= 1) r += __shfl_xor(r, off, 64);
            if (d == 0) out[(size_t)b * 400 + 100 + (o - 100)] = r;
        }
    }
    __syncthreads();
    #pragma unroll
    for (int n = 0; n < 100; ++n) hr[n] = hs[n][d];

    for (int oi = 0; oi < 25; ++oi) {
        const int o = o0 + oi;
        const float* __restrict__ wrow = w3 + (size_t)o * 4000;
        float s = b3[o];
        for (int m = 0; m < 40; ++m) {
            const float* __restrict__ wm = wrow + m * 100;
            float a0 = 0.f, a1 = 0.f, a2 = 0.f, a3 = 0.f;
            #pragma unroll
            for (int n = 0; n < 100; n += 4) {
                a0 = fmaf(wm[n + 0], hr[n + 0], a0);
                a1 = fmaf(wm[n + 1], hr[n + 1], a1);
                a2 = fmaf(wm[n + 2], hr[n + 2], a2);
                a3 = fmaf(wm[n + 3], hr[n + 3], a3);
            }
            s = fmaf(xs[m][d], (a0 + a1) + (a2 + a3), s);
        }
        s = fmaxf(s, 0.f);
        float r = s;
        #pragma unroll
        for (int off = 32; off > 0; off >>= 1) r += __shfl_xor(r, off, 64);
        if (d == 0) out[(size_t)b * 400 + 200 + o] = r;
    }
}

extern "C" void kernel_launch(void* const* d_in, const int* in_sizes, int n_in,
                              void* d_out, int out_size, void* d_ws, size_t ws_size,
                              hipStream_t stream) {
    const float* x  = (const float*)d_in[0];
    const float* w1 = (const float*)d_in[1];
    const float* b1 = (const float*)d_in[2];
    const float* w2 = (const float*)d_in[3];
    const float* b2 = (const float*)d_in[4];
    const float* w3 = (const float*)d_in[5];
    const float* b3 = (const float*)d_in[6];
    float* out = (float*)d_out;

    if (ws_size >= 248000u * 16u) {
        uint4* wp = (uint4*)d_ws;
        convert_pack32<<<dim3(969), dim3(256), 0, stream>>>(w1, w2, w3, wp);
        fused_mfma32<<<dim3(256), dim3(512), 0, stream>>>(
            x, (const bf16x8*)wp, b1, b2, b3, out);
    } else {
        fused_bilinear_kernel<<<dim3(512), dim3(512), 0, stream>>>(
            x, w1, b1, w2, b2, w3, b3, out);
    }
}

// Round 12
// 158.636 us; speedup vs baseline: 2.3513x; 2.3513x over previous
//
#include <hip/hip_runtime.h>
#include <hip/hip_bf16.h>

// ============================================================================
// B=512, M=40, D=64. Three bilinear layers (200 outputs each):
//   out[o,d] = relu(bias[o] + sum_c W[o,c]*U[c,d]), U[(m,n),d] = x[m,d]*h[n,d]
// Per b: GEMM C[208,64] = W[208,K] x U[K,64] bf16, K=1600/4000/4000.
// R12 = R5 structure with 4-kstep phases and 8 U-slabs:
//   - barrier count halved (1 per 4 ksteps instead of 2)
//   - A-frag slot reloaded right after its consume for kstep+8 -> full-phase
//     latency cover (~1200 cyc >> L2 latency)
//   - build-to-consume slack: slab written 1-2 phases before its read
// Block = 2 batches, grid 256 (1/CU), 8 waves = 4 gm (m-tiles 4/3/3/3) x 2 wn.
// U XOR position perm (R5-verified): logical uint u of row d at dword
//   2*((u>>1)^((d>>1)&7)) + (u&1). Raw s_barrier + lgkmcnt(0) only (A-frag
//   global loads are wave-private, fly across barriers - no vmcnt drain).
// ============================================================================

typedef float f32x4 __attribute__((ext_vector_type(4)));
typedef short bf16x8 __attribute__((ext_vector_type(8)));
typedef unsigned int uint;

#define XS_STR 44     // bf16; 88B rows
#define HS_STR 108    // bf16; 216B rows

struct LDSState {
    __hip_bfloat16 xs[2][64][XS_STR];     // [bb][d][m]         11264 B
    __hip_bfloat16 hs[2][2][64][HS_STR];  // [pp][bb][d][n]     55296 B
    uint U[8][2][64][16];                 // [slab][bb][d][pos] 65536 B
};                                        // total 132096 B -> 1 block/CU

static __device__ __forceinline__ float bflo(uint u) {
    uint v = u << 16; return __builtin_bit_cast(float, v);
}
static __device__ __forceinline__ float bfhi(uint u) {
    uint v = u & 0xffff0000u; return __builtin_bit_cast(float, v);
}
static __device__ __forceinline__ uint pk_bf16(float a, float b) {
    uint r; asm("v_cvt_pk_bf16_f32 %0, %1, %2" : "=v"(r) : "v"(a), "v"(b));
    return r;
}

#define PHASE_BAR() do {                                   \
    asm volatile("s_waitcnt lgkmcnt(0)" ::: "memory");     \
    __builtin_amdgcn_sched_barrier(0);                     \
    __builtin_amdgcn_s_barrier();                          \
    __builtin_amdgcn_sched_barrier(0);                     \
} while (0)

template<int DIV, int NK, int HASH, int ROWLO, int ROWOFF, int HSTR, int A>
__device__ __forceinline__ void layer_core(
    LDSState* L, const bf16x8* __restrict__ wpk, const float* __restrict__ bias,
    const __hip_bfloat16* __restrict__ h0, const __hip_bfloat16* __restrict__ h1,
    int dstpp, float* outb0, float* outb1, int tid, int mt0)
{
    const int lane = tid & 63;
    const int wv = tid >> 6, wn = wv & 1;
    const int q = lane >> 4, lr = lane & 15, d = lane;

    // consume read bases (R5-verified perm); slab stride 2048 dwords
    const int hdr = (lr >> 1) & 7;
    const uint* ub  = &L->U[0][0][0][0] + wn * 1024;
    const uint* roA = ub + (lr * 16 + 2 * ((2 * q) ^ hdr));
    const uint* roB = ub + (lr * 16 + 2 * ((2 * q + 1) ^ hdr));

    // build write base: wave wv owns k-slots 4wv..4wv+3 (uints 2wv,2wv+1)
    const int hdw = (d >> 1) & 7;
    uint* wb = &L->U[0][0][d][0] + 2 * (wv ^ hdw);

    const __hip_bfloat16* xb0 = &L->xs[0][d][0];
    const __hip_bfloat16* xb1 = &L->xs[1][d][0];
    const __hip_bfloat16* hb0 = h0 + d * HSTR;
    const __hip_bfloat16* hb1 = h1 + d * HSTR;

    f32x4 acc[A][4];
    #pragma unroll
    for (int mi = 0; mi < A; ++mi)
        #pragma unroll
        for (int nj = 0; nj < 4; ++nj)
            acc[mi][nj] = {0.f, 0.f, 0.f, 0.f};

    // build state machine: kstep bk covers k-slots c0 = 32*bk + 4*wv .. +3
    int bm = (4 * wv) / DIV;
    int bn = (4 * wv) % DIV;
    int bk = 0;
    auto build = [&]() {
        if (bk < NK) {
            const int slab_dw = (bk & 7) * 2048;
            float xf0 = __bfloat162float(xb0[bm]);
            float xf1 = __bfloat162float(xb1[bm]);
            uint2 ha = *(const uint2*)(hb0 + bn);
            uint2 hc = *(const uint2*)(hb1 + bn);
            uint2 w0, w1;
            w0.x = pk_bf16(xf0 * bflo(ha.x), xf0 * bfhi(ha.x));
            w0.y = pk_bf16(xf0 * bflo(ha.y), xf0 * bfhi(ha.y));
            w1.x = pk_bf16(xf1 * bflo(hc.x), xf1 * bfhi(hc.x));
            w1.y = pk_bf16(xf1 * bflo(hc.y), xf1 * bfhi(hc.y));
            *(uint2*)(wb + slab_dw)        = w0;
            *(uint2*)(wb + slab_dw + 1024) = w1;
            bn += 32;
            if (bn >= DIV) { bn -= DIV; ++bm; }
            ++bk;
        }
    };

    auto consume = [&](int slab_dw, bf16x8* f) {
        bf16x8 bv[4];
        #pragma unroll
        for (int nj = 0; nj < 4; ++nj) {
            union { uint2 u2[2]; bf16x8 v; } t;
            t.u2[0] = *(const uint2*)(roA + slab_dw + nj * 256);
            t.u2[1] = *(const uint2*)(roB + slab_dw + nj * 256);
            bv[nj] = t.v;
        }
        #pragma unroll
        for (int mi = 0; mi < A; ++mi)
            #pragma unroll
            for (int nj = 0; nj < 4; ++nj)
                acc[mi][nj] = __builtin_amdgcn_mfma_f32_16x16x32_bf16(
                    f[mi], bv[nj], acc[mi][nj], 0, 0, 0);
    };

    const bf16x8* pw = wpk + (size_t)mt0 * NK * 64 + lane;
    auto loadf = [&](bf16x8* f, int s) {
        if (s < NK) {
            #pragma unroll
            for (int mi = 0; mi < A; ++mi)
                f[mi] = pw[(size_t)mi * NK * 64 + (size_t)s * 64];
        }
    };

    bf16x8 a0[A], a1[A], a2[A], a3[A], b0[A], b1[A], b2[A], b3[A];
    loadf(a0, 0); loadf(a1, 1); loadf(a2, 2); loadf(a3, 3);
    loadf(b0, 4); loadf(b1, 5); loadf(b2, 6); loadf(b3, 7);
    build(); build(); build(); build();     // ksteps 0-3 -> slabs 0-3
    __syncthreads();

    #pragma unroll 1
    for (int s = 0; s + 8 <= NK; s += 8) {
        // phase A: consume ksteps s..s+3 (slabs 0-3); build s+4..s+7 (4-7)
        consume(0 * 2048, a0); loadf(a0, s + 8);
        consume(1 * 2048, a1); loadf(a1, s + 9);
        consume(2 * 2048, a2); loadf(a2, s + 10);
        consume(3 * 2048, a3); loadf(a3, s + 11);
        build(); build(); build(); build();
        PHASE_BAR();
        // phase B: consume s+4..s+7 (slabs 4-7); build s+8..s+11 (slabs 0-3)
        consume(4 * 2048, b0); loadf(b0, s + 12);
        consume(5 * 2048, b1); loadf(b1, s + 13);
        consume(6 * 2048, b2); loadf(b2, s + 14);
        consume(7 * 2048, b3); loadf(b3, s + 15);
        build(); build(); build(); build();
        PHASE_BAR();
    }
    // tail: REM = NK % 8 ksteps remain, in slabs 0..REM-1 (built; frags in
    // a0..a3 / b0). REM = 2 (NK=50) or 5 (NK=125).
    constexpr int REM = NK % 8;
    if constexpr (REM >= 1) consume(0 * 2048, a0);
    if constexpr (REM >= 2) consume(1 * 2048, a1);
    if constexpr (REM >= 3) consume(2 * 2048, a2);
    if constexpr (REM >= 4) consume(3 * 2048, a3);
    if constexpr (REM == 5) {
        build();                 // kstep NK-1 -> slab 4
        PHASE_BAR();
        consume(4 * 2048, b0);
    }

    // epilogue: C/D layout row = 4q+reg, col = lr (m89-verified)
    float* outp = wn ? outb1 : outb0;
    #pragma unroll
    for (int mi = 0; mi < A; ++mi) {
        const int mt = mt0 + mi;
        #pragma unroll
        for (int reg = 0; reg < 4; ++reg) {
            const int o = 16 * mt + 4 * q + reg;
            if (o < 200) {
                const float bs = bias[o];
                float r0 = fmaxf(acc[mi][0][reg] + bs, 0.f);
                float r1 = fmaxf(acc[mi][1][reg] + bs, 0.f);
                float r2 = fmaxf(acc[mi][2][reg] + bs, 0.f);
                float r3 = fmaxf(acc[mi][3][reg] + bs, 0.f);
                if (HASH && o < 100) {
                    L->hs[dstpp][wn][ 0 + lr][o] = __float2bfloat16(r0);
                    L->hs[dstpp][wn][16 + lr][o] = __float2bfloat16(r1);
                    L->hs[dstpp][wn][32 + lr][o] = __float2bfloat16(r2);
                    L->hs[dstpp][wn][48 + lr][o] = __float2bfloat16(r3);
                }
                if (o >= ROWLO) {
                    float sv = (r0 + r1) + (r2 + r3);
                    sv += __shfl_xor(sv, 1, 64);
                    sv += __shfl_xor(sv, 2, 64);
                    sv += __shfl_xor(sv, 4, 64);
                    sv += __shfl_xor(sv, 8, 64);
                    if (lr == 0) outp[ROWOFF + (o - ROWLO)] = sv;
                }
            }
        }
    }
    __syncthreads();
}

template<int A>
__device__ __forceinline__ void run_layers(
    LDSState* L, const bf16x8* w1p, const bf16x8* w2p, const bf16x8* w3p,
    const float* b1, const float* b2, const float* b3,
    float* outb0, float* outb1, int tid, int mt0)
{
    layer_core< 40,  50, 1, 100,   0, XS_STR, A>(L, w1p, b1,
        &L->xs[0][0][0], &L->xs[1][0][0], 0, outb0, outb1, tid, mt0);
    layer_core<100, 125, 1, 100, 100, HS_STR, A>(L, w2p, b2,
        &L->hs[0][0][0][0], &L->hs[0][1][0][0], 1, outb0, outb1, tid, mt0);
    layer_core<100, 125, 0,   0, 200, HS_STR, A>(L, w3p, b3,
        &L->hs[1][0][0][0], &L->hs[1][1][0][0], 0, outb0, outb1, tid, mt0);
}

__global__ __launch_bounds__(512, 2)
void fused_mfma(const float* __restrict__ x,
                const bf16x8* __restrict__ wpk,
                const float* __restrict__ b1, const float* __restrict__ b2,
                const float* __restrict__ b3, float* __restrict__ out) {
    __shared__ LDSState L;
    const int tid = threadIdx.x;
    const int bi  = blockIdx.x;

    // stage x (2 b's), fp32 -> bf16, transposed to [d][m]
    const float* xg = x + (size_t)(2 * bi) * 2560;
    for (int i = tid; i < 5120; i += 512) {
        int bb = (i >= 2560) ? 1 : 0;
        int r  = i - bb * 2560;
        L.xs[bb][r & 63][r >> 6] = __float2bfloat16(xg[(size_t)bb * 2560 + r]);
    }
    __syncthreads();

    float* outb0 = out + (size_t)(2 * bi + 0) * 400;
    float* outb1 = out + (size_t)(2 * bi + 1) * 400;

    const bf16x8* w1p = wpk;              // 13*50*64  = 41600 frags
    const bf16x8* w2p = wpk + 41600;      // 13*125*64 = 104000
    const bf16x8* w3p = wpk + 145600;

    const int wm = tid >> 7;              // wave-pair id 0..3
    if (wm == 0)
        run_layers<4>(&L, w1p, w2p, w3p, b1, b2, b3, outb0, outb1, tid, 0);
    else
        run_layers<3>(&L, w1p, w2p, w3p, b1, b2, b3, outb0, outb1, tid,
                      3 * wm + 1);
}

// ---------------------------------------------------------------------------
// Prepass: repack W fp32 -> bf16 frag-contiguous. Element c = one lane's
// bf16x8: c = layerbase + (mt*NK + s)*64 + lane, holding
// W[16*mt + (lane&15), 32*s + 8*(lane>>4) .. +8]  (rows >= 200 zero).
// ---------------------------------------------------------------------------
__global__ void convert_pack(const float* __restrict__ w1, const float* __restrict__ w2,
                             const float* __restrict__ w3, uint4* __restrict__ outp) {
    int c = blockIdx.x * 256 + threadIdx.x;
    if (c >= 249600) return;
    const float* src; int K, base;
    if (c < 41600)       { src = w1; K = 1600; base = c; }
    else if (c < 145600) { src = w2; K = 4000; base = c - 41600; }
    else                 { src = w3; K = 4000; base = c - 145600; }
    const int NS   = K / 32;
    const int lane = base & 63;
    const int t    = base >> 6;
    const int mt   = t / NS;
    const int s    = t - mt * NS;
    const int row  = 16 * mt + (lane & 15);
    const int k0   = 32 * s + 8 * (lane >> 4);
    uint o[4];
    if (row < 200) {
        const float* p = src + (size_t)row * K + k0;
        #pragma unroll
        for (int j = 0; j < 4; ++j) {
            __hip_bfloat16 lo = __float2bfloat16(p[2 * j]);
            __hip_bfloat16 hi = __float2bfloat16(p[2 * j + 1]);
            o[j] = (uint)__builtin_bit_cast(unsigned short, lo)
                 | ((uint)__builtin_bit_cast(unsigned short, hi) << 16);
        }
    } else {
        #pragma unroll
        for (int j = 0; j < 4; ++j) o[j] = 0u;
    }
    uint4 v; v.x = o[0]; v.y = o[1]; v.z = o[2]; v.w = o[3];
    outp[c] = v;
}

// ---------------------------------------------------------------------------
// Fallback (fp32 VALU kernel) if ws too small.
// ---------------------------------------------------------------------------
__global__ __launch_bounds__(512, 1)
void fused_bilinear_kernel(const float* __restrict__ x,
                           const float* __restrict__ w1, const float* __restrict__ b1,
                           const float* __restrict__ w2, const float* __restrict__ b2,
                           const float* __restrict__ w3, const float* __restrict__ b3,
                           float* __restrict__ out) {
    const int b   = blockIdx.x;
    const int tid = threadIdx.x;
    const int d   = tid & 63;
    const int wv  = tid >> 6;

    __shared__ float xs[40][64];
    __shared__ float hs[100][64];

    const float* xb = x + (size_t)b * 40 * 64;
    for (int i = tid; i < 40 * 64; i += 512) ((float*)xs)[i] = xb[i];
    __syncthreads();

    float xr[40];
    #pragma unroll
    for (int m = 0; m < 40; ++m) xr[m] = xs[m][d];
    float hr[100];
    const int o0 = __builtin_amdgcn_readfirstlane(wv * 25);

    for (int oi = 0; oi < 25; ++oi) {
        const int o = o0 + oi;
        const float* __restrict__ wrow = w1 + (size_t)o * 1600;
        float s = b1[o];
        for (int m = 0; m < 40; ++m) {
            const float* __restrict__ wm = wrow + m * 40;
            float a0 = 0.f, a1 = 0.f, a2 = 0.f, a3 = 0.f;
            #pragma unroll
            for (int n = 0; n < 40; n += 4) {
                a0 = fmaf(wm[n + 0], xr[n + 0], a0);
                a1 = fmaf(wm[n + 1], xr[n + 1], a1);
                a2 = fmaf(wm[n + 2], xr[n + 2], a2);
                a3 = fmaf(wm[n + 3], xr[n + 3], a3);
            }
            s = fmaf(xs[m][d], (a0 + a1) + (a2 + a3), s);
        }
        s = fmaxf(s, 0.f);
        if (o < 100) hs[o][d] = s;
        else {
            float r = s;
            #pragma unroll
            for (int off = 32; off > 0; off >>= 1) r += __shfl_xor(r, off, 64);
            if (d == 0) out[(size_t)b * 400 + (o - 100)] = r;
        }
    }
    __syncthreads();
    #pragma unroll
    for (int n = 0; n < 100; ++n) hr[n] = hs[n][d];
    __syncthreads();

    for (int oi = 0; oi < 25; ++oi) {
        const int o = o0 + oi;
        const float* __restrict__ wrow = w2 + (size_t)o * 4000;
        float s = b2[o];
        for (int m = 0; m < 40; ++m) {
            const float* __restrict__ wm = wrow + m * 100;
            float a0 = 0.f, a1 = 0.f, a2 = 0.f, a3 = 0.f;
            #pragma unroll
            for (int n = 0; n < 100; n += 4) {
                a0 = fmaf(wm[n + 0], hr[n + 0], a0);
                a1 = fmaf(wm[n + 1], hr[n + 1], a1);
                a2 = fmaf(wm[n + 2], hr[n + 2], a2);
                a3 = fmaf(wm[n + 3], hr[n + 3], a3);
            }
            s = fmaf(xs[m][d], (a0 + a1) + (a2 + a3), s);
        }
        s = fmaxf(s, 0.f);
        if (o < 100) hs[o][d] = s;
        else {
            float r = s;
            #pragma unroll
            for (int off = 32; off > 0; off >>= 1) r += __shfl_xor(r, off, 64);
            if (d == 0) out[(size_t)b * 400 + 100 + (o - 100)] = r;
        }
    }
    __syncthreads();
    #pragma unroll
    for (int n = 0; n < 100; ++n) hr[n] = hs[n][d];

    for (int oi = 0; oi < 25; ++oi) {
        const int o = o0 + oi;
        const float* __restrict__ wrow = w3 + (size_t)o * 4000;
        float s = b3[o];
        for (int m = 0; m < 40; ++m) {
            const float* __restrict__ wm = wrow + m * 100;
            float a0 = 0.f, a1 = 0.f, a2 = 0.f, a3 = 0.f;
            #pragma unroll
            for (int n = 0; n < 100; n += 4) {
                a0 = fmaf(wm[n + 0], hr[n + 0], a0);
                a1 = fmaf(wm[n + 1], hr[n + 1], a1);
                a2 = fmaf(wm[n + 2], hr[n + 2], a2);
                a3 = fmaf(wm[n + 3], hr[n + 3], a3);
            }
            s = fmaf(xs[m][d], (a0 + a1) + (a2 + a3), s);
        }
        s = fmaxf(s, 0.f);
        float r = s;
        #pragma unroll
        for (int off = 32; off > 0; off >>= 1) r += __shfl_xor(r, off, 64);
        if (d == 0) out[(size_t)b * 400 + 200 + o] = r;
    }
}

extern "C" void kernel_launch(void* const* d_in, const int* in_sizes, int n_in,
                              void* d_out, int out_size, void* d_ws, size_t ws_size,
                              hipStream_t stream) {
    const float* x  = (const float*)d_in[0];
    const float* w1 = (const float*)d_in[1];
    const float* b1 = (const float*)d_in[2];
    const float* w2 = (const float*)d_in[3];
    const float* b2 = (const float*)d_in[4];
    const float* w3 = (const float*)d_in[5];
    const float* b3 = (const float*)d_in[6];
    float* out = (float*)d_out;

    if (ws_size >= 249600u * 16u) {
        uint4* wp = (uint4*)d_ws;
        convert_pack<<<dim3(975), dim3(256), 0, stream>>>(w1, w2, w3, wp);
        fused_mfma<<<dim3(256), dim3(512), 0, stream>>>(
            x, (const bf16x8*)wp, b1, b2, b3, out);
    } else {
        fused_bilinear_kernel<<<dim3(512), dim3(512), 0, stream>>>(
            x, w1, b1, w2, b2, w3, b3, out);
    }
}